// Round 1
// baseline (140.816 us; speedup 1.0000x reference)
//
#include <hip/hip_runtime.h>
#include <cstdint>

#define NB 32
#define NL 512
#define NE 256
#define NH 8
#define ND 64
#define NM 16384   // NB*NL
#define NHD 512    // NH*ND

using half8 = __attribute__((ext_vector_type(8))) _Float16;
using half4 = __attribute__((ext_vector_type(4))) _Float16;
using f32x4 = __attribute__((ext_vector_type(4))) float;

__device__ __forceinline__ f32x4 mfma16(half8 a, half8 b, f32x4 c) {
    return __builtin_amdgcn_mfma_f32_16x16x32_f16(a, b, c, 0, 0, 0);
}

// async global->LDS, 16B per lane. LDS dest = wave-uniform base + lane*16.
__device__ __forceinline__ void cp16_g2l(const void* g, void* l) {
    __builtin_amdgcn_global_load_lds(
        (const __attribute__((address_space(1))) void*)g,
        (__attribute__((address_space(3))) void*)l, 16, 0, 0);
}

// ---------------- K0: repack weights to f16, K-contiguous ----------------
// wqkv: [1536][256]  row n = (s*512 + h*64 + d), col = e ; value = W_s[h,e,d]
// woh : [256][512]   row e, col f ; value = Wo[f,e]
__global__ __launch_bounds__(256) void prep_weights(
        const float* __restrict__ Wq, const float* __restrict__ Wk,
        const float* __restrict__ Wv, const float* __restrict__ Wo,
        _Float16* __restrict__ wqkv, _Float16* __restrict__ woh) {
    int idx = blockIdx.x * 256 + threadIdx.x;
    if (idx < 1536 * 256) {
        int n = idx >> 8, e = idx & 255;
        int s = n >> 9, h = (n >> 6) & 7, d = n & 63;
        const float* W = (s == 0) ? Wq : (s == 1) ? Wk : Wv;
        wqkv[idx] = (_Float16)W[(h * NE + e) * ND + d];
    } else {
        int j = idx - 1536 * 256;           // 0 .. 131071
        int e = j >> 9, f = j & 511;
        woh[j] = (_Float16)Wo[f * NE + e];
    }
}

// ---------------- K1: xph = f16(x + positional) ----------------
__global__ __launch_bounds__(256) void make_xph(
        const float* __restrict__ x, const float* __restrict__ pos,
        _Float16* __restrict__ xph) {
    int i = (blockIdx.x * 256 + threadIdx.x) * 4;   // over 16384*256 elems
    float4 xv = *(const float4*)(x + i);
    float4 pv = *(const float4*)(pos + (i & (NL * NE - 1)));
    half4 o;
    o[0] = (_Float16)(xv.x + pv.x);
    o[1] = (_Float16)(xv.y + pv.y);
    o[2] = (_Float16)(xv.z + pv.z);
    o[3] = (_Float16)(xv.w + pv.w);
    *(half4*)(xph + i) = o;
}

// ---------------- K2: fused QKV projection GEMM (C^T form) ----------------
// Ct[n][m] = sum_e wqkv[n][e] * xph[m][e], then tanh, route to q/k/v.
// 128(n) x 128(m) tile, 4 waves (2x2), 16x16x32 f16 MFMA, BK=32.
__global__ __launch_bounds__(256) void proj_gemm(
        const _Float16* __restrict__ wqkv, const _Float16* __restrict__ xph,
        _Float16* __restrict__ q_all, _Float16* __restrict__ k_all,
        _Float16* __restrict__ v_all) {
    __shared__ _Float16 Alds[128 * 32];
    __shared__ _Float16 Blds[128 * 32];
    int tid = threadIdx.x;
    int w = tid >> 6, l = tid & 63;
    int tn = blockIdx.x % 12, tm = blockIdx.x / 12;
    int wn = w >> 1, wm = w & 1;
    int m16 = l & 15, g = l >> 4;
    f32x4 acc[4][4] = {};

    for (int kt = 0; kt < 8; ++kt) {
#pragma unroll
        for (int i = 0; i < 2; ++i) {
            int chunk = w * 2 + i;                 // 0..7 (1024B chunks)
            int row = chunk * 16 + (l >> 2);       // 0..127
            int kc = (l & 3) * 8;                  // f16 k-offset
            cp16_g2l(wqkv + (size_t)(tn * 128 + row) * 256 + kt * 32 + kc,
                     Alds + chunk * 512);
            cp16_g2l(xph + (size_t)(tm * 128 + row) * 256 + kt * 32 + kc,
                     Blds + chunk * 512);
        }
        __syncthreads();
        half8 a[4], b[4];
#pragma unroll
        for (int f = 0; f < 4; ++f) {
            a[f] = *(const half8*)(Alds + (wn * 64 + f * 16 + m16) * 32 + g * 8);
            b[f] = *(const half8*)(Blds + (wm * 64 + f * 16 + m16) * 32 + g * 8);
        }
#pragma unroll
        for (int nf = 0; nf < 4; ++nf)
#pragma unroll
            for (int mf = 0; mf < 4; ++mf)
                acc[nf][mf] = mfma16(a[nf], b[mf], acc[nf][mf]);
        __syncthreads();
    }
    // epilogue: n-dim = 4 consecutive output cols -> packed 8B stores
#pragma unroll
    for (int nf = 0; nf < 4; ++nf) {
        int n = tn * 128 + wn * 64 + nf * 16 + g * 4;
        int s = n >> 9, c = n & 511;
        _Float16* dst = (s == 0) ? q_all : (s == 1) ? k_all : v_all;
#pragma unroll
        for (int mf = 0; mf < 4; ++mf) {
            int m = tm * 128 + wm * 64 + mf * 16 + m16;
            f32x4 v = acc[nf][mf];
            half4 hv;
#pragma unroll
            for (int r = 0; r < 4; ++r) hv[r] = (_Float16)tanhf(v[r]);
            *(half4*)(dst + (size_t)m * NHD + c) = hv;
        }
    }
}

// ---------------- K3: flash attention ----------------
// block = (b, h, qtile of 128); 8 waves, each wave owns 16 q-rows.
// K, V^T staged in XOR-swizzled LDS; online softmax; P via wave-private LDS.
__global__ __launch_bounds__(512) void attn_kernel(
        const _Float16* __restrict__ q_all, const _Float16* __restrict__ k_all,
        const _Float16* __restrict__ v_all, _Float16* __restrict__ attn_out) {
    __shared__ _Float16 Klds[64 * 64];    // [key][d], groups of 8 XOR (key&7)
    __shared__ _Float16 Vtlds[64 * 64];   // [d][key], groups of 8 XOR (d>>3)
    __shared__ _Float16 Plds[8][16 * 64]; // per wave [q16][key64], XOR (row&7)
    int tid = threadIdx.x;
    int w = tid >> 6, l = tid & 63;
    int bid = blockIdx.x;
    int qt = bid & 3, h = (bid >> 2) & 7, b = bid >> 5;
    int m16 = l & 15, g = l >> 4;

    // Q fragments from global (reused over all k-tiles)
    size_t qoff = (size_t)(b * NL + qt * 128 + w * 16 + m16) * NHD + h * ND + g * 8;
    half8 qf[2];
    qf[0] = *(const half8*)(q_all + qoff);
    qf[1] = *(const half8*)(q_all + qoff + 32);

    f32x4 acc_o[4] = {};
    float mrow[4], lrow[4];
#pragma unroll
    for (int r = 0; r < 4; ++r) { mrow[r] = -1e30f; lrow[r] = 0.f; }

    int srow = tid >> 3;   // 0..63 (key)
    int sdg = tid & 7;     // 0..7  (8-elem d-chunk)
    const _Float16* kg = k_all + (size_t)(b * NL + srow) * NHD + h * ND + sdg * 8;
    const _Float16* vg = v_all + (size_t)(b * NL + srow) * NHD + h * ND + sdg * 8;
    int koff = srow * 64 + ((sdg ^ (srow & 7)) << 3);

    for (int kt = 0; kt < 8; ++kt) {
        // stage K (row-major, swizzled)
        uint4 kv = *(const uint4*)(kg + (size_t)kt * 64 * NHD);
        *(uint4*)&Klds[koff] = kv;
        // stage V transposed: Vt[d][key]
        uint4 vv = *(const uint4*)(vg + (size_t)kt * 64 * NHD);
        const _Float16* hv = (const _Float16*)&vv;
#pragma unroll
        for (int j = 0; j < 8; ++j) {
            int d = sdg * 8 + j;
            Vtlds[d * 64 + (((srow >> 3) ^ sdg) << 3) + (srow & 7)] = hv[j];
        }
        __syncthreads();

        // S = Q K^T  (16 q x 64 key per wave)
        f32x4 acc_s[4] = {};
#pragma unroll
        for (int ks = 0; ks < 2; ++ks)
#pragma unroll
            for (int n = 0; n < 4; ++n) {
                int key = n * 16 + m16;
                half8 kb = *(const half8*)(Klds + key * 64 +
                                           (((ks * 4 + g) ^ (key & 7)) << 3));
                acc_s[n] = mfma16(qf[ks], kb, acc_s[n]);
            }

        // online softmax (rows (g*4+r), cols n*16+m16; scale 1/8)
        float tmax[4];
#pragma unroll
        for (int r = 0; r < 4; ++r) {
            float t = fmaxf(fmaxf(acc_s[0][r], acc_s[1][r]),
                            fmaxf(acc_s[2][r], acc_s[3][r])) * 0.125f;
            t = fmaxf(t, __shfl_xor(t, 1));
            t = fmaxf(t, __shfl_xor(t, 2));
            t = fmaxf(t, __shfl_xor(t, 4));
            t = fmaxf(t, __shfl_xor(t, 8));
            tmax[r] = t;
        }
        float alpha[4], rsum[4];
#pragma unroll
        for (int r = 0; r < 4; ++r) {
            float mn = fmaxf(mrow[r], tmax[r]);
            alpha[r] = __expf(mrow[r] - mn);
            mrow[r] = mn;
            rsum[r] = 0.f;
        }
#pragma unroll
        for (int n = 0; n < 4; ++n) {
            int colg = 2 * n + (m16 >> 3);
#pragma unroll
            for (int r = 0; r < 4; ++r) {
                int row = g * 4 + r;
                float p = __expf(acc_s[n][r] * 0.125f - mrow[r]);
                rsum[r] += p;
                Plds[w][row * 64 + ((colg ^ (row & 7)) << 3) + (m16 & 7)] =
                    (_Float16)p;
            }
        }
#pragma unroll
        for (int r = 0; r < 4; ++r) {
            float t = rsum[r];
            t += __shfl_xor(t, 1);
            t += __shfl_xor(t, 2);
            t += __shfl_xor(t, 4);
            t += __shfl_xor(t, 8);
            lrow[r] = lrow[r] * alpha[r] + t;
#pragma unroll
            for (int n = 0; n < 4; ++n) acc_o[n][r] *= alpha[r];
        }
        // O += P V
#pragma unroll
        for (int ks = 0; ks < 2; ++ks) {
            half8 pa = *(const half8*)(Plds[w] + m16 * 64 +
                                       (((ks * 4 + g) ^ (m16 & 7)) << 3));
#pragma unroll
            for (int n = 0; n < 4; ++n) {
                int d = n * 16 + m16;
                half8 vb = *(const half8*)(Vtlds + d * 64 +
                                           (((ks * 4 + g) ^ (d >> 3)) << 3));
                acc_o[n] = mfma16(pa, vb, acc_o[n]);
            }
        }
        __syncthreads();
    }
    // epilogue: attn_out[b*L + q][h*64 + d]
    int qg = qt * 128 + w * 16 + g * 4;
#pragma unroll
    for (int r = 0; r < 4; ++r) {
        float inv = 1.f / lrow[r];
#pragma unroll
        for (int n = 0; n < 4; ++n)
            attn_out[(size_t)(b * NL + qg + r) * NHD + h * ND + n * 16 + m16] =
                (_Float16)(acc_o[n][r] * inv);
    }
}

// ---------------- K4: output projection + fp32 tanh residual ----------------
// Ct[e][m] = sum_f woh[e][f]*attn[m][f];  out[m][e] = Ct + tanh(x+pos)
__global__ __launch_bounds__(256) void final_gemm(
        const _Float16* __restrict__ woh, const _Float16* __restrict__ attn,
        const float* __restrict__ x, const float* __restrict__ pos,
        float* __restrict__ out) {
    __shared__ _Float16 Alds[128 * 32];
    __shared__ _Float16 Blds[128 * 32];
    int tid = threadIdx.x;
    int w = tid >> 6, l = tid & 63;
    int tn = blockIdx.x & 1, tm = blockIdx.x >> 1;
    int wn = w >> 1, wm = w & 1;
    int m16 = l & 15, g = l >> 4;
    f32x4 acc[4][4] = {};

    for (int kt = 0; kt < 16; ++kt) {
#pragma unroll
        for (int i = 0; i < 2; ++i) {
            int chunk = w * 2 + i;
            int row = chunk * 16 + (l >> 2);
            int kc = (l & 3) * 8;
            cp16_g2l(woh + (size_t)(tn * 128 + row) * 512 + kt * 32 + kc,
                     Alds + chunk * 512);
            cp16_g2l(attn + (size_t)(tm * 128 + row) * 512 + kt * 32 + kc,
                     Blds + chunk * 512);
        }
        __syncthreads();
        half8 a[4], b[4];
#pragma unroll
        for (int f = 0; f < 4; ++f) {
            a[f] = *(const half8*)(Alds + (wn * 64 + f * 16 + m16) * 32 + g * 8);
            b[f] = *(const half8*)(Blds + (wm * 64 + f * 16 + m16) * 32 + g * 8);
        }
#pragma unroll
        for (int nf = 0; nf < 4; ++nf)
#pragma unroll
            for (int mf = 0; mf < 4; ++mf)
                acc[nf][mf] = mfma16(a[nf], b[mf], acc[nf][mf]);
        __syncthreads();
    }
#pragma unroll
    for (int nf = 0; nf < 4; ++nf) {
        int e = tn * 128 + wn * 64 + nf * 16 + g * 4;
#pragma unroll
        for (int mf = 0; mf < 4; ++mf) {
            int m = tm * 128 + wm * 64 + mf * 16 + m16;
            int lr = m & (NL - 1);
            float4 xv = *(const float4*)(x + (size_t)m * NE + e);
            float4 pv = *(const float4*)(pos + (size_t)lr * NE + e);
            f32x4 v = acc[nf][mf];
            float4 o;
            o.x = v[0] + tanhf(xv.x + pv.x);
            o.y = v[1] + tanhf(xv.y + pv.y);
            o.z = v[2] + tanhf(xv.z + pv.z);
            o.w = v[3] + tanhf(xv.w + pv.w);
            *(float4*)(out + (size_t)m * NE + e) = o;
        }
    }
}

extern "C" void kernel_launch(void* const* d_in, const int* in_sizes, int n_in,
                              void* d_out, int out_size, void* d_ws, size_t ws_size,
                              hipStream_t stream) {
    const float* x   = (const float*)d_in[0];
    const float* pos = (const float*)d_in[1];
    const float* Wq  = (const float*)d_in[2];
    const float* Wk  = (const float*)d_in[3];
    const float* Wv  = (const float*)d_in[4];
    const float* Wo  = (const float*)d_in[5];
    float* out = (float*)d_out;

    char* ws = (char*)d_ws;
    _Float16* xph   = (_Float16*)(ws);                    //  8,388,608 B
    _Float16* wqkv  = (_Float16*)(ws + 8388608);          //    786,432 B
    _Float16* woh   = (_Float16*)(ws + 9175040);          //    262,144 B
    _Float16* q_all = (_Float16*)(ws + 9437184);          // 16,777,216 B
    _Float16* k_all = (_Float16*)(ws + 26214400);         // 16,777,216 B
    _Float16* v_all = (_Float16*)(ws + 42991616);         // 16,777,216 B
    _Float16* attn  = (_Float16*)(ws + 59768832);         // 16,777,216 B -> 76.5MB

    prep_weights<<<dim3(2048), dim3(256), 0, stream>>>(Wq, Wk, Wv, Wo, wqkv, woh);
    make_xph<<<dim3(4096), dim3(256), 0, stream>>>(x, pos, xph);
    proj_gemm<<<dim3(12 * 128), dim3(256), 0, stream>>>(wqkv, xph, q_all, k_all, v_all);
    attn_kernel<<<dim3(1024), dim3(512), 0, stream>>>(q_all, k_all, v_all, attn);
    final_gemm<<<dim3(256), dim3(256), 0, stream>>>(woh, attn, x, pos, out);
}

// Round 2
// 101.883 us; speedup vs baseline: 1.3821x; 1.3821x over previous
//
#include <hip/hip_runtime.h>
#include <cstdint>

#define NB 32
#define NL 512
#define NE 256
#define NH 8
#define ND 64
#define NM 16384   // NB*NL
#define NHD 512    // NH*ND

using half8  = __attribute__((ext_vector_type(8))) _Float16;
using half4  = __attribute__((ext_vector_type(4))) _Float16;
using f32x4  = __attribute__((ext_vector_type(4))) float;
using f32x16 = __attribute__((ext_vector_type(16))) float;

__device__ __forceinline__ f32x4 mfma16(half8 a, half8 b, f32x4 c) {
    return __builtin_amdgcn_mfma_f32_16x16x32_f16(a, b, c, 0, 0, 0);
}
__device__ __forceinline__ f32x16 mfma32(half8 a, half8 b, f32x16 c) {
    return __builtin_amdgcn_mfma_f32_32x32x16_f16(a, b, c, 0, 0, 0);
}
// async global->LDS, 16B/lane; LDS dest = wave-uniform base + lane*16.
__device__ __forceinline__ void cp16_g2l(const void* g, void* l) {
    __builtin_amdgcn_global_load_lds(
        (const __attribute__((address_space(1))) void*)g,
        (__attribute__((address_space(3))) void*)l, 16, 0, 0);
}

// ---------------- K0: fused weight repack + xph = f16(x+pos) ----------------
__global__ __launch_bounds__(256) void prep(
        const float* __restrict__ x, const float* __restrict__ pos,
        const float* __restrict__ Wq, const float* __restrict__ Wk,
        const float* __restrict__ Wv, const float* __restrict__ Wo,
        _Float16* __restrict__ wqkv, _Float16* __restrict__ woh,
        _Float16* __restrict__ xph) {
    int bid = blockIdx.x;
    if (bid < 2048) {
        int idx = bid * 256 + threadIdx.x;
        if (idx < 1536 * 256) {
            int n = idx >> 8, e = idx & 255;
            int s = n >> 9, h = (n >> 6) & 7, d = n & 63;
            const float* W = (s == 0) ? Wq : (s == 1) ? Wk : Wv;
            wqkv[idx] = (_Float16)W[(h * NE + e) * ND + d];
        } else {
            int j = idx - 1536 * 256;
            int e = j >> 9, f = j & 511;
            woh[j] = (_Float16)Wo[f * NE + e];
        }
    } else {
        int i = ((bid - 2048) * 256 + threadIdx.x) * 4;
        float4 xv = *(const float4*)(x + i);
        float4 pv = *(const float4*)(pos + (i & (NL * NE - 1)));
        half4 o;
        o[0] = (_Float16)(xv.x + pv.x);
        o[1] = (_Float16)(xv.y + pv.y);
        o[2] = (_Float16)(xv.z + pv.z);
        o[3] = (_Float16)(xv.w + pv.w);
        *(half4*)(xph + i) = o;
    }
}

// ---------------- K1: fused QKV projection GEMM ----------------
// q,k blocks (tn<8): Ct[n][m], tanh, store [token][c] (d-contig).
// v blocks (tn>=8): operand-swapped mfma -> D[token][c], store vT[c][token].
// BK=64, 128B LDS rows, XOR-swizzled via pre-swizzled global_load_lds source.
__global__ __launch_bounds__(256) void proj_gemm(
        const _Float16* __restrict__ wqkv, const _Float16* __restrict__ xph,
        _Float16* __restrict__ q_all, _Float16* __restrict__ k_all,
        _Float16* __restrict__ vT) {
    __shared__ _Float16 Alds[128 * 64];
    __shared__ _Float16 Blds[128 * 64];
    int tid = threadIdx.x;
    int w = tid >> 6, l = tid & 63;
    int tn = blockIdx.x % 12, tm = blockIdx.x / 12;
    int wn = w >> 1, wm = w & 1;
    int m16 = l & 15, g = l >> 4;
    bool isv = (tn >= 8);
    int lrow8 = l >> 3;             // row within 8-row chunk
    int kc16 = (l & 7) ^ lrow8;     // pre-swizzled global 16B k-unit
    f32x4 acc[4][4] = {};

    for (int kt = 0; kt < 4; ++kt) {
#pragma unroll
        for (int i = 0; i < 4; ++i) {
            int cA = w * 4 + i;                 // 16 chunks of 1KB each
            int row = cA * 8 + lrow8;
            cp16_g2l(wqkv + (size_t)(tn * 128 + row) * 256 + kt * 64 + kc16 * 8,
                     Alds + cA * 512);
            cp16_g2l(xph + (size_t)(tm * 128 + row) * 256 + kt * 64 + kc16 * 8,
                     Blds + cA * 512);
        }
        __syncthreads();
#pragma unroll
        for (int ks = 0; ks < 2; ++ks) {
            half8 af[4], bf[4];
#pragma unroll
            for (int f = 0; f < 4; ++f) {
                int ra = wn * 64 + f * 16 + m16;
                int rb = wm * 64 + f * 16 + m16;
                af[f] = *(const half8*)(Alds + ra * 64 + (((ks * 4 + g) ^ (ra & 7)) << 3));
                bf[f] = *(const half8*)(Blds + rb * 64 + (((ks * 4 + g) ^ (rb & 7)) << 3));
            }
            if (!isv) {
#pragma unroll
                for (int nf = 0; nf < 4; ++nf)
#pragma unroll
                    for (int mf = 0; mf < 4; ++mf)
                        acc[nf][mf] = mfma16(af[nf], bf[mf], acc[nf][mf]);
            } else {
#pragma unroll
                for (int nf = 0; nf < 4; ++nf)
#pragma unroll
                    for (int mf = 0; mf < 4; ++mf)
                        acc[nf][mf] = mfma16(bf[mf], af[nf], acc[nf][mf]);
            }
        }
        __syncthreads();
    }
    if (!isv) {
        _Float16* dst = (tn < 4) ? q_all : k_all;
#pragma unroll
        for (int nf = 0; nf < 4; ++nf) {
            int c = (tn & 3) * 128 + wn * 64 + nf * 16 + g * 4;
#pragma unroll
            for (int mf = 0; mf < 4; ++mf) {
                int m = tm * 128 + wm * 64 + mf * 16 + m16;
                f32x4 v = acc[nf][mf];
                half4 hv;
#pragma unroll
                for (int r = 0; r < 4; ++r) hv[r] = (_Float16)tanhf(v[r]);
                *(half4*)(dst + (size_t)m * NHD + c) = hv;
            }
        }
    } else {
#pragma unroll
        for (int nf = 0; nf < 4; ++nf) {
            int c = (tn - 8) * 128 + wn * 64 + nf * 16 + m16;
#pragma unroll
            for (int mf = 0; mf < 4; ++mf) {
                int t0 = tm * 128 + wm * 64 + mf * 16 + g * 4;
                f32x4 v = acc[nf][mf];    // rows = tokens t0+r, col = c
                half4 hv;
#pragma unroll
                for (int r = 0; r < 4; ++r) hv[r] = (_Float16)tanhf(v[r]);
                *(half4*)(vT + (size_t)c * NM + t0) = hv;
            }
        }
    }
}

// ---------------- K2: flash attention, 32x32x16 MFMA ----------------
// 4 waves x 32 q-rows = 128 q/block; KV tiles of 64; S^T = mfma(K,Q) so each
// lane owns one q-row -> in-register softmax + 1 shuffle; defer-max (THR=8).
__global__ __launch_bounds__(256, 3) void attn_kernel(
        const _Float16* __restrict__ q_all, const _Float16* __restrict__ k_all,
        const _Float16* __restrict__ vT, _Float16* __restrict__ attn_out) {
    __shared__ _Float16 Klds[2][64 * 64];   // [key][d], unit^=(key&7)
    __shared__ _Float16 Vtlds[2][64 * 64];  // [d][key], unit^=(d&7)
    __shared__ _Float16 Plds[4][32 * 64];   // per-wave [q][key], unit^=(q&7)
    int tid = threadIdx.x;
    int w = tid >> 6, l = tid & 63;
    int l31 = l & 31, hi = l >> 5;
    int bid = blockIdx.x;
    int qt = bid & 3, h = (bid >> 2) & 7, b = bid >> 5;

    int qbase = qt * 128 + w * 32;
    half8 qf[4];   // B operand: [q=l31][d = ks*16 + hi*8]
    {
        const _Float16* qp = q_all + (size_t)(b * NL + qbase + l31) * NHD + h * ND + hi * 8;
#pragma unroll
        for (int ks = 0; ks < 4; ++ks) qf[ks] = *(const half8*)(qp + ks * 16);
    }

    f32x16 acc_o[2] = {};
    float mrow = -1e30f, lrow = 0.f;

    int st_row = tid >> 2;          // K: key / Vt: d
    int st_u0 = (tid & 3) * 2;      // two 16B units per thread
    const _Float16* kg = k_all + (size_t)(b * NL + st_row) * NHD + h * ND + st_u0 * 8;
    const _Float16* vg = vT + (size_t)(h * ND + st_row) * NM + b * NL + st_u0 * 8;
    int so0 = st_row * 64 + ((st_u0 ^ (st_row & 7)) << 3);
    int so1 = st_row * 64 + (((st_u0 + 1) ^ (st_row & 7)) << 3);

    uint4 kv0 = *(const uint4*)(kg);
    uint4 kv1 = *(const uint4*)(kg + 8);
    uint4 vv0 = *(const uint4*)(vg);
    uint4 vv1 = *(const uint4*)(vg + 8);
    *(uint4*)&Klds[0][so0] = kv0;   *(uint4*)&Klds[0][so1] = kv1;
    *(uint4*)&Vtlds[0][so0] = vv0;  *(uint4*)&Vtlds[0][so1] = vv1;
    __syncthreads();

    for (int kt = 0; kt < 8; ++kt) {
        int cur = kt & 1;
        if (kt < 7) {   // issue next-tile loads early (hide under compute)
            const _Float16* kp = kg + (size_t)(kt + 1) * 64 * NHD;
            const _Float16* vp = vg + (kt + 1) * 64;
            kv0 = *(const uint4*)(kp);      kv1 = *(const uint4*)(kp + 8);
            vv0 = *(const uint4*)(vp);      vv1 = *(const uint4*)(vp + 8);
        }
        // S^T = K Q^T : acc_s[kb2] rows=keys, cols=q
        f32x16 acc_s[2] = {};
#pragma unroll
        for (int ks = 0; ks < 4; ++ks)
#pragma unroll
            for (int kb2 = 0; kb2 < 2; ++kb2) {
                int key = kb2 * 32 + l31;
                half8 kb = *(const half8*)(&Klds[cur][key * 64 + (((ks * 2 + hi) ^ (key & 7)) << 3)]);
                acc_s[kb2] = mfma32(kb, qf[ks], acc_s[kb2]);
            }
        // online softmax, q = l31 per lane
        float mx = -1e30f;
#pragma unroll
        for (int kb2 = 0; kb2 < 2; ++kb2)
#pragma unroll
            for (int j = 0; j < 16; ++j) mx = fmaxf(mx, acc_s[kb2][j]);
        mx = fmaxf(mx, __shfl_xor(mx, 32));
        mx *= 0.125f;
        if (!__all(mx <= mrow + 8.f)) {   // defer-max: rescale rarely fires
            float mn = fmaxf(mrow, mx);
            float alpha = __expf(mrow - mn);
            mrow = mn;
            lrow *= alpha;
            float aq[16];
#pragma unroll
            for (int c = 0; c < 4; ++c)
#pragma unroll
                for (int r = 0; r < 4; ++r)
                    aq[c * 4 + r] = __shfl(alpha, c * 8 + hi * 4 + r);
#pragma unroll
            for (int d2 = 0; d2 < 2; ++d2)
#pragma unroll
                for (int j = 0; j < 16; ++j) acc_o[d2][j] *= aq[j];
        }
        float rs = 0.f;
#pragma unroll
        for (int kb2 = 0; kb2 < 2; ++kb2)
#pragma unroll
            for (int c = 0; c < 4; ++c) {
                half4 hv;
#pragma unroll
                for (int r = 0; r < 4; ++r) {
                    float p = __expf(acc_s[kb2][c * 4 + r] * 0.125f - mrow);
                    rs += p;
                    hv[r] = (_Float16)p;
                }
                int u = kb2 * 4 + c;   // keys u*8 + hi*4 + r
                *(half4*)(&Plds[w][l31 * 64 + ((u ^ (l31 & 7)) << 3) + hi * 4]) = hv;
            }
        rs += __shfl_xor(rs, 32);
        lrow += rs;
        // O += P V
#pragma unroll
        for (int ks = 0; ks < 4; ++ks) {
            half8 pa = *(const half8*)(&Plds[w][l31 * 64 + (((ks * 2 + hi) ^ (l31 & 7)) << 3)]);
#pragma unroll
            for (int d2 = 0; d2 < 2; ++d2) {
                int d = d2 * 32 + l31;
                half8 vb = *(const half8*)(&Vtlds[cur][d * 64 + (((ks * 2 + hi) ^ (d & 7)) << 3)]);
                acc_o[d2] = mfma32(pa, vb, acc_o[d2]);
            }
        }
        if (kt < 7) {   // write prefetched tile, single barrier per tile
            int nxt = cur ^ 1;
            *(uint4*)&Klds[nxt][so0] = kv0;   *(uint4*)&Klds[nxt][so1] = kv1;
            *(uint4*)&Vtlds[nxt][so0] = vv0;  *(uint4*)&Vtlds[nxt][so1] = vv1;
            __syncthreads();
        }
    }
    // epilogue: O[q][d], rows q from reg mapping, col d = d2*32 + l31
    size_t orow0 = (size_t)(b * NL + qbase);
#pragma unroll
    for (int c = 0; c < 4; ++c)
#pragma unroll
        for (int r = 0; r < 4; ++r) {
            int qrow = c * 8 + hi * 4 + r;
            float inv = 1.f / __shfl(lrow, qrow);
#pragma unroll
            for (int d2 = 0; d2 < 2; ++d2)
                attn_out[(orow0 + qrow) * NHD + h * ND + d2 * 32 + l31] =
                    (_Float16)(acc_o[d2][c * 4 + r] * inv);
        }
}

// ---------------- K3: output projection + fp32 tanh residual ----------------
// tile 128e x 64m -> 512 blocks (2/CU). BK=64, swizzled LDS as in proj_gemm.
__global__ __launch_bounds__(256) void final_gemm(
        const _Float16* __restrict__ woh, const _Float16* __restrict__ attn,
        const float* __restrict__ x, const float* __restrict__ pos,
        float* __restrict__ out) {
    __shared__ _Float16 Alds[128 * 64];
    __shared__ _Float16 Blds[64 * 64];
    int tid = threadIdx.x;
    int w = tid >> 6, l = tid & 63;
    int tn = blockIdx.x & 1, tm = blockIdx.x >> 1;
    int wn = w >> 1, wm = w & 1;
    int m16 = l & 15, g = l >> 4;
    int lrow8 = l >> 3;
    int kc16 = (l & 7) ^ lrow8;
    f32x4 acc[4][2] = {};

    for (int kt = 0; kt < 8; ++kt) {
#pragma unroll
        for (int i = 0; i < 4; ++i) {
            int cA = w * 4 + i;
            int row = cA * 8 + lrow8;
            cp16_g2l(woh + (size_t)(tn * 128 + row) * 512 + kt * 64 + kc16 * 8,
                     Alds + cA * 512);
        }
#pragma unroll
        for (int i = 0; i < 2; ++i) {
            int cB = w * 2 + i;
            int row = cB * 8 + lrow8;
            cp16_g2l(attn + (size_t)(tm * 64 + row) * 512 + kt * 64 + kc16 * 8,
                     Blds + cB * 512);
        }
        __syncthreads();
#pragma unroll
        for (int ks = 0; ks < 2; ++ks) {
            half8 af[4], bf[2];
#pragma unroll
            for (int f = 0; f < 4; ++f) {
                int ra = wn * 64 + f * 16 + m16;
                af[f] = *(const half8*)(Alds + ra * 64 + (((ks * 4 + g) ^ (ra & 7)) << 3));
            }
#pragma unroll
            for (int f = 0; f < 2; ++f) {
                int rb = wm * 32 + f * 16 + m16;
                bf[f] = *(const half8*)(Blds + rb * 64 + (((ks * 4 + g) ^ (rb & 7)) << 3));
            }
#pragma unroll
            for (int nf = 0; nf < 4; ++nf)
#pragma unroll
                for (int mf = 0; mf < 2; ++mf)
                    acc[nf][mf] = mfma16(af[nf], bf[mf], acc[nf][mf]);
        }
        __syncthreads();
    }
#pragma unroll
    for (int nf = 0; nf < 4; ++nf) {
        int e = tn * 128 + wn * 64 + nf * 16 + g * 4;
#pragma unroll
        for (int mf = 0; mf < 2; ++mf) {
            int m = tm * 64 + wm * 32 + mf * 16 + m16;
            int lr = m & (NL - 1);
            float4 xv = *(const float4*)(x + (size_t)m * NE + e);
            float4 pv = *(const float4*)(pos + (size_t)lr * NE + e);
            f32x4 v = acc[nf][mf];
            float4 o;
            o.x = v[0] + tanhf(xv.x + pv.x);
            o.y = v[1] + tanhf(xv.y + pv.y);
            o.z = v[2] + tanhf(xv.z + pv.z);
            o.w = v[3] + tanhf(xv.w + pv.w);
            *(float4*)(out + (size_t)m * NE + e) = o;
        }
    }
}

extern "C" void kernel_launch(void* const* d_in, const int* in_sizes, int n_in,
                              void* d_out, int out_size, void* d_ws, size_t ws_size,
                              hipStream_t stream) {
    const float* x   = (const float*)d_in[0];
    const float* pos = (const float*)d_in[1];
    const float* Wq  = (const float*)d_in[2];
    const float* Wk  = (const float*)d_in[3];
    const float* Wv  = (const float*)d_in[4];
    const float* Wo  = (const float*)d_in[5];
    float* out = (float*)d_out;

    char* ws = (char*)d_ws;
    _Float16* xph   = (_Float16*)(ws);              //  8,388,608 B
    _Float16* wqkv  = (_Float16*)(ws + 8388608);    //    786,432 B
    _Float16* woh   = (_Float16*)(ws + 9175040);    //    262,144 B
    _Float16* q_all = (_Float16*)(ws + 9437184);    // 16,777,216 B
    _Float16* k_all = (_Float16*)(ws + 26214400);   // 16,777,216 B
    _Float16* vT    = (_Float16*)(ws + 42991616);   // 16,777,216 B [c][token]
    _Float16* attn  = (_Float16*)(ws + 59768832);   // 16,777,216 B

    prep<<<dim3(6144), dim3(256), 0, stream>>>(x, pos, Wq, Wk, Wv, Wo, wqkv, woh, xph);
    proj_gemm<<<dim3(12 * 128), dim3(256), 0, stream>>>(wqkv, xph, q_all, k_all, vT);
    attn_kernel<<<dim3(1024), dim3(256), 0, stream>>>(q_all, k_all, vT, attn);
    final_gemm<<<dim3(512), dim3(256), 0, stream>>>(woh, attn, x, pos, out);
}

// Round 3
// 84.272 us; speedup vs baseline: 1.6710x; 1.2090x over previous
//
#include <hip/hip_runtime.h>
#include <cstdint>

#define NB 32
#define NL 512
#define NE 256
#define NH 8
#define ND 64
#define NM 16384   // NB*NL
#define NHD 512    // NH*ND

using half8  = __attribute__((ext_vector_type(8))) _Float16;
using half4  = __attribute__((ext_vector_type(4))) _Float16;
using f32x4  = __attribute__((ext_vector_type(4))) float;
using f32x16 = __attribute__((ext_vector_type(16))) float;

__device__ __forceinline__ f32x4 mfma16(half8 a, half8 b, f32x4 c) {
    return __builtin_amdgcn_mfma_f32_16x16x32_f16(a, b, c, 0, 0, 0);
}
__device__ __forceinline__ f32x16 mfma32(half8 a, half8 b, f32x16 c) {
    return __builtin_amdgcn_mfma_f32_32x32x16_f16(a, b, c, 0, 0, 0);
}
// async global->LDS, 16B/lane; LDS dest = wave-uniform base + lane*16.
__device__ __forceinline__ void cp16_g2l(const void* g, void* l) {
    __builtin_amdgcn_global_load_lds(
        (const __attribute__((address_space(1))) void*)g,
        (__attribute__((address_space(3))) void*)l, 16, 0, 0);
}
// fast tanh: ~6 ops, 2 on TRANS pipe. |err| ~1e-6, invisible under f16.
__device__ __forceinline__ float fast_tanh(float x) {
    float xc = fminf(fmaxf(x, -9.f), 9.f);
    float t = __expf(2.f * xc);
    return (t - 1.f) * __builtin_amdgcn_rcpf(t + 1.f);
}

// ---------------- K0: fused weight repack + xph = f16(x+pos) ----------------
__global__ __launch_bounds__(256) void prep(
        const float* __restrict__ x, const float* __restrict__ pos,
        const float* __restrict__ Wq, const float* __restrict__ Wk,
        const float* __restrict__ Wv, const float* __restrict__ Wo,
        _Float16* __restrict__ wqkv, _Float16* __restrict__ woh,
        _Float16* __restrict__ xph) {
    int bid = blockIdx.x;
    if (bid < 2048) {
        int idx = bid * 256 + threadIdx.x;
        if (idx < 1536 * 256) {
            int n = idx >> 8, e = idx & 255;
            int s = n >> 9, h = (n >> 6) & 7, d = n & 63;
            const float* W = (s == 0) ? Wq : (s == 1) ? Wk : Wv;
            wqkv[idx] = (_Float16)W[(h * NE + e) * ND + d];
        } else {
            int j = idx - 1536 * 256;
            int e = j >> 9, f = j & 511;
            woh[j] = (_Float16)Wo[f * NE + e];
        }
    } else {
        int i = ((bid - 2048) * 256 + threadIdx.x) * 4;
        float4 xv = *(const float4*)(x + i);
        float4 pv = *(const float4*)(pos + (i & (NL * NE - 1)));
        half4 o;
        o[0] = (_Float16)(xv.x + pv.x);
        o[1] = (_Float16)(xv.y + pv.y);
        o[2] = (_Float16)(xv.z + pv.z);
        o[3] = (_Float16)(xv.w + pv.w);
        *(half4*)(xph + i) = o;
    }
}

// ---------------- K1: fused QKV projection GEMM ----------------
// q,k blocks (tn<8): Ct[n][m], tanh, store [token][c] (d-contig).
// v blocks (tn>=8): operand-swapped mfma -> D[token][c], store vT[c][token].
// BK=64, 128B LDS rows, XOR-swizzled via pre-swizzled global_load_lds source.
// Grid: XCD-chunked bijective remap (1536 = 8 x 12 x 16).
__global__ __launch_bounds__(256) void proj_gemm(
        const _Float16* __restrict__ wqkv, const _Float16* __restrict__ xph,
        _Float16* __restrict__ q_all, _Float16* __restrict__ k_all,
        _Float16* __restrict__ vT) {
    __shared__ _Float16 Alds[128 * 64];
    __shared__ _Float16 Blds[128 * 64];
    int tid = threadIdx.x;
    int w = tid >> 6, l = tid & 63;
    int bid = blockIdx.x;
    int xcd = bid & 7, local = bid >> 3;        // local in [0,192)
    int tn = local % 12;
    int tm = xcd * 16 + local / 12;             // contiguous tm chunk per XCD
    int wn = w >> 1, wm = w & 1;
    int m16 = l & 15, g = l >> 4;
    bool isv = (tn >= 8);
    int lrow8 = l >> 3;             // row within 8-row chunk
    int kc16 = (l & 7) ^ lrow8;     // pre-swizzled global 16B k-unit
    f32x4 acc[4][4] = {};

    for (int kt = 0; kt < 4; ++kt) {
#pragma unroll
        for (int i = 0; i < 4; ++i) {
            int cA = w * 4 + i;                 // 16 chunks of 1KB each
            int row = cA * 8 + lrow8;
            cp16_g2l(wqkv + (size_t)(tn * 128 + row) * 256 + kt * 64 + kc16 * 8,
                     Alds + cA * 512);
            cp16_g2l(xph + (size_t)(tm * 128 + row) * 256 + kt * 64 + kc16 * 8,
                     Blds + cA * 512);
        }
        __syncthreads();
#pragma unroll
        for (int ks = 0; ks < 2; ++ks) {
            half8 af[4], bf[4];
#pragma unroll
            for (int f = 0; f < 4; ++f) {
                int ra = wn * 64 + f * 16 + m16;
                int rb = wm * 64 + f * 16 + m16;
                af[f] = *(const half8*)(Alds + ra * 64 + (((ks * 4 + g) ^ (ra & 7)) << 3));
                bf[f] = *(const half8*)(Blds + rb * 64 + (((ks * 4 + g) ^ (rb & 7)) << 3));
            }
            if (!isv) {
#pragma unroll
                for (int nf = 0; nf < 4; ++nf)
#pragma unroll
                    for (int mf = 0; mf < 4; ++mf)
                        acc[nf][mf] = mfma16(af[nf], bf[mf], acc[nf][mf]);
            } else {
#pragma unroll
                for (int nf = 0; nf < 4; ++nf)
#pragma unroll
                    for (int mf = 0; mf < 4; ++mf)
                        acc[nf][mf] = mfma16(bf[mf], af[nf], acc[nf][mf]);
            }
        }
        __syncthreads();
    }
    if (!isv) {
        _Float16* dst = (tn < 4) ? q_all : k_all;
#pragma unroll
        for (int nf = 0; nf < 4; ++nf) {
            int c = (tn & 3) * 128 + wn * 64 + nf * 16 + g * 4;
#pragma unroll
            for (int mf = 0; mf < 4; ++mf) {
                int m = tm * 128 + wm * 64 + mf * 16 + m16;
                f32x4 v = acc[nf][mf];
                half4 hv;
#pragma unroll
                for (int r = 0; r < 4; ++r) hv[r] = (_Float16)fast_tanh(v[r]);
                *(half4*)(dst + (size_t)m * NHD + c) = hv;
            }
        }
    } else {
#pragma unroll
        for (int nf = 0; nf < 4; ++nf) {
            int c = (tn - 8) * 128 + wn * 64 + nf * 16 + m16;
#pragma unroll
            for (int mf = 0; mf < 4; ++mf) {
                int t0 = tm * 128 + wm * 64 + mf * 16 + g * 4;
                f32x4 v = acc[nf][mf];    // rows = tokens t0+r, col = c
                half4 hv;
#pragma unroll
                for (int r = 0; r < 4; ++r) hv[r] = (_Float16)fast_tanh(v[r]);
                *(half4*)(vT + (size_t)c * NM + t0) = hv;
            }
        }
    }
}

// ---------------- K2: flash attention, 32x32x16 MFMA ----------------
// 4 waves x 32 q-rows = 128 q/block; KV tiles of 64; S^T = mfma(K,Q) so each
// lane owns one q-row -> in-register softmax + 1 shuffle; defer-max (THR=8).
__global__ __launch_bounds__(256, 3) void attn_kernel(
        const _Float16* __restrict__ q_all, const _Float16* __restrict__ k_all,
        const _Float16* __restrict__ vT, _Float16* __restrict__ attn_out) {
    __shared__ _Float16 Klds[2][64 * 64];   // [key][d], unit^=(key&7)
    __shared__ _Float16 Vtlds[2][64 * 64];  // [d][key], unit^=(d&7)
    __shared__ _Float16 Plds[4][32 * 64];   // per-wave [q][key], unit^=(q&7)
    int tid = threadIdx.x;
    int w = tid >> 6, l = tid & 63;
    int l31 = l & 31, hi = l >> 5;
    int bid = blockIdx.x;
    int qt = bid & 3, h = (bid >> 2) & 7, b = bid >> 5;

    int qbase = qt * 128 + w * 32;
    half8 qf[4];   // B operand: [q=l31][d = ks*16 + hi*8]
    {
        const _Float16* qp = q_all + (size_t)(b * NL + qbase + l31) * NHD + h * ND + hi * 8;
#pragma unroll
        for (int ks = 0; ks < 4; ++ks) qf[ks] = *(const half8*)(qp + ks * 16);
    }

    f32x16 acc_o[2] = {};
    float mrow = -1e30f, lrow = 0.f;

    int st_row = tid >> 2;          // K: key / Vt: d
    int st_u0 = (tid & 3) * 2;      // two 16B units per thread
    const _Float16* kg = k_all + (size_t)(b * NL + st_row) * NHD + h * ND + st_u0 * 8;
    const _Float16* vg = vT + (size_t)(h * ND + st_row) * NM + b * NL + st_u0 * 8;
    int so0 = st_row * 64 + ((st_u0 ^ (st_row & 7)) << 3);
    int so1 = st_row * 64 + (((st_u0 + 1) ^ (st_row & 7)) << 3);

    uint4 kv0 = *(const uint4*)(kg);
    uint4 kv1 = *(const uint4*)(kg + 8);
    uint4 vv0 = *(const uint4*)(vg);
    uint4 vv1 = *(const uint4*)(vg + 8);
    *(uint4*)&Klds[0][so0] = kv0;   *(uint4*)&Klds[0][so1] = kv1;
    *(uint4*)&Vtlds[0][so0] = vv0;  *(uint4*)&Vtlds[0][so1] = vv1;
    __syncthreads();

    for (int kt = 0; kt < 8; ++kt) {
        int cur = kt & 1;
        if (kt < 7) {   // issue next-tile loads early (hide under compute)
            const _Float16* kp = kg + (size_t)(kt + 1) * 64 * NHD;
            const _Float16* vp = vg + (kt + 1) * 64;
            kv0 = *(const uint4*)(kp);      kv1 = *(const uint4*)(kp + 8);
            vv0 = *(const uint4*)(vp);      vv1 = *(const uint4*)(vp + 8);
        }
        // S^T = K Q^T : acc_s[kb2] rows=keys, cols=q
        f32x16 acc_s[2] = {};
#pragma unroll
        for (int ks = 0; ks < 4; ++ks)
#pragma unroll
            for (int kb2 = 0; kb2 < 2; ++kb2) {
                int key = kb2 * 32 + l31;
                half8 kb = *(const half8*)(&Klds[cur][key * 64 + (((ks * 2 + hi) ^ (key & 7)) << 3)]);
                acc_s[kb2] = mfma32(kb, qf[ks], acc_s[kb2]);
            }
        // online softmax, q = l31 per lane
        float mx = -1e30f;
#pragma unroll
        for (int kb2 = 0; kb2 < 2; ++kb2)
#pragma unroll
            for (int j = 0; j < 16; ++j) mx = fmaxf(mx, acc_s[kb2][j]);
        mx = fmaxf(mx, __shfl_xor(mx, 32));
        mx *= 0.125f;
        if (!__all(mx <= mrow + 8.f)) {   // defer-max: rescale rarely fires
            float mn = fmaxf(mrow, mx);
            float alpha = __expf(mrow - mn);
            mrow = mn;
            lrow *= alpha;
            float aq[16];
#pragma unroll
            for (int c = 0; c < 4; ++c)
#pragma unroll
                for (int r = 0; r < 4; ++r)
                    aq[c * 4 + r] = __shfl(alpha, c * 8 + hi * 4 + r);
#pragma unroll
            for (int d2 = 0; d2 < 2; ++d2)
#pragma unroll
                for (int j = 0; j < 16; ++j) acc_o[d2][j] *= aq[j];
        }
        float rs = 0.f;
#pragma unroll
        for (int kb2 = 0; kb2 < 2; ++kb2)
#pragma unroll
            for (int c = 0; c < 4; ++c) {
                half4 hv;
#pragma unroll
                for (int r = 0; r < 4; ++r) {
                    float p = __expf(acc_s[kb2][c * 4 + r] * 0.125f - mrow);
                    rs += p;
                    hv[r] = (_Float16)p;
                }
                int u = kb2 * 4 + c;   // keys u*8 + hi*4 + r
                *(half4*)(&Plds[w][l31 * 64 + ((u ^ (l31 & 7)) << 3) + hi * 4]) = hv;
            }
        rs += __shfl_xor(rs, 32);
        lrow += rs;
        // O += P V
#pragma unroll
        for (int ks = 0; ks < 4; ++ks) {
            half8 pa = *(const half8*)(&Plds[w][l31 * 64 + (((ks * 2 + hi) ^ (l31 & 7)) << 3)]);
#pragma unroll
            for (int d2 = 0; d2 < 2; ++d2) {
                int d = d2 * 32 + l31;
                half8 vb = *(const half8*)(&Vtlds[cur][d * 64 + (((ks * 2 + hi) ^ (d & 7)) << 3)]);
                acc_o[d2] = mfma32(pa, vb, acc_o[d2]);
            }
        }
        if (kt < 7) {   // write prefetched tile, single barrier per tile
            int nxt = cur ^ 1;
            *(uint4*)&Klds[nxt][so0] = kv0;   *(uint4*)&Klds[nxt][so1] = kv1;
            *(uint4*)&Vtlds[nxt][so0] = vv0;  *(uint4*)&Vtlds[nxt][so1] = vv1;
            __syncthreads();
        }
    }
    // epilogue: O[q][d], rows q from reg mapping, col d = d2*32 + l31
    size_t orow0 = (size_t)(b * NL + qbase);
#pragma unroll
    for (int c = 0; c < 4; ++c)
#pragma unroll
        for (int r = 0; r < 4; ++r) {
            int qrow = c * 8 + hi * 4 + r;
            float inv = 1.f / __shfl(lrow, qrow);
#pragma unroll
            for (int d2 = 0; d2 < 2; ++d2)
                attn_out[(orow0 + qrow) * NHD + h * ND + d2 * 32 + l31] =
                    (_Float16)(acc_o[d2][c * 4 + r] * inv);
        }
}

// ---------------- K3: output projection + fp32 tanh residual ----------------
// tile 128e x 64m -> 512 blocks (2/CU). BK=64, swizzled LDS as in proj_gemm.
__global__ __launch_bounds__(256) void final_gemm(
        const _Float16* __restrict__ woh, const _Float16* __restrict__ attn,
        const float* __restrict__ x, const float* __restrict__ pos,
        float* __restrict__ out) {
    __shared__ _Float16 Alds[128 * 64];
    __shared__ _Float16 Blds[64 * 64];
    int tid = threadIdx.x;
    int w = tid >> 6, l = tid & 63;
    int tn = blockIdx.x & 1, tm = blockIdx.x >> 1;
    int wn = w >> 1, wm = w & 1;
    int m16 = l & 15, g = l >> 4;
    int lrow8 = l >> 3;
    int kc16 = (l & 7) ^ lrow8;
    f32x4 acc[4][2] = {};

    for (int kt = 0; kt < 8; ++kt) {
#pragma unroll
        for (int i = 0; i < 4; ++i) {
            int cA = w * 4 + i;
            int row = cA * 8 + lrow8;
            cp16_g2l(woh + (size_t)(tn * 128 + row) * 512 + kt * 64 + kc16 * 8,
                     Alds + cA * 512);
        }
#pragma unroll
        for (int i = 0; i < 2; ++i) {
            int cB = w * 2 + i;
            int row = cB * 8 + lrow8;
            cp16_g2l(attn + (size_t)(tm * 64 + row) * 512 + kt * 64 + kc16 * 8,
                     Blds + cB * 512);
        }
        __syncthreads();
#pragma unroll
        for (int ks = 0; ks < 2; ++ks) {
            half8 af[4], bf[2];
#pragma unroll
            for (int f = 0; f < 4; ++f) {
                int ra = wn * 64 + f * 16 + m16;
                af[f] = *(const half8*)(Alds + ra * 64 + (((ks * 4 + g) ^ (ra & 7)) << 3));
            }
#pragma unroll
            for (int f = 0; f < 2; ++f) {
                int rb = wm * 32 + f * 16 + m16;
                bf[f] = *(const half8*)(Blds + rb * 64 + (((ks * 4 + g) ^ (rb & 7)) << 3));
            }
#pragma unroll
            for (int nf = 0; nf < 4; ++nf)
#pragma unroll
                for (int mf = 0; mf < 2; ++mf)
                    acc[nf][mf] = mfma16(af[nf], bf[mf], acc[nf][mf]);
        }
        __syncthreads();
    }
#pragma unroll
    for (int nf = 0; nf < 4; ++nf) {
        int e = tn * 128 + wn * 64 + nf * 16 + g * 4;
#pragma unroll
        for (int mf = 0; mf < 2; ++mf) {
            int m = tm * 64 + wm * 32 + mf * 16 + m16;
            int lr = m & (NL - 1);
            float4 xv = *(const float4*)(x + (size_t)m * NE + e);
            float4 pv = *(const float4*)(pos + (size_t)lr * NE + e);
            f32x4 v = acc[nf][mf];
            float4 o;
            o.x = v[0] + fast_tanh(xv.x + pv.x);
            o.y = v[1] + fast_tanh(xv.y + pv.y);
            o.z = v[2] + fast_tanh(xv.z + pv.z);
            o.w = v[3] + fast_tanh(xv.w + pv.w);
            *(float4*)(out + (size_t)m * NE + e) = o;
        }
    }
}

extern "C" void kernel_launch(void* const* d_in, const int* in_sizes, int n_in,
                              void* d_out, int out_size, void* d_ws, size_t ws_size,
                              hipStream_t stream) {
    const float* x   = (const float*)d_in[0];
    const float* pos = (const float*)d_in[1];
    const float* Wq  = (const float*)d_in[2];
    const float* Wk  = (const float*)d_in[3];
    const float* Wv  = (const float*)d_in[4];
    const float* Wo  = (const float*)d_in[5];
    float* out = (float*)d_out;

    char* ws = (char*)d_ws;
    _Float16* xph   = (_Float16*)(ws);              //  8,388,608 B
    _Float16* wqkv  = (_Float16*)(ws + 8388608);    //    786,432 B
    _Float16* woh   = (_Float16*)(ws + 9175040);    //    262,144 B
    _Float16* q_all = (_Float16*)(ws + 9437184);    // 16,777,216 B
    _Float16* k_all = (_Float16*)(ws + 26214400);   // 16,777,216 B
    _Float16* vT    = (_Float16*)(ws + 42991616);   // 16,777,216 B [c][token]
    _Float16* attn  = (_Float16*)(ws + 59768832);   // 16,777,216 B

    prep<<<dim3(6144), dim3(256), 0, stream>>>(x, pos, Wq, Wk, Wv, Wo, wqkv, woh, xph);
    proj_gemm<<<dim3(12 * 128), dim3(256), 0, stream>>>(wqkv, xph, q_all, k_all, vT);
    attn_kernel<<<dim3(1024), dim3(256), 0, stream>>>(q_all, k_all, vT, attn);
    final_gemm<<<dim3(512), dim3(256), 0, stream>>>(woh, attn, x, pos, out);
}